// Round 4
// baseline (5874.593 us; speedup 1.0000x reference)
//
#include <hip/hip_runtime.h>
#include <cstdint>
#include <cstddef>

#define TSTEPS 100
#define NB 256
#define INF 2312
#define HIDN 512
#define NOUT 10

// ws layout (float offsets)
#define OFF_WT  0                 // 262144 floats (w_rec transposed, 1 MB)
#define OFF_ZG  262144            // 8192 floats = 2 x 2048 u64 z-mask buffers
#define OFF_CTR 270336            // barrier counter (64-float slot)
#define OFF_CI  270400            // 13107200 floats (input-projection cache)
#define WS_FLOATS 13377600        // ~53.5 MB

// build w_recT[r][h] = w_rec[h][r]; zero z buffers + barrier counter
__global__ __launch_bounds__(256) void init_kernel(float* __restrict__ ws,
                                                   const float* __restrict__ w_rec) {
    int n = blockIdx.x * 256 + threadIdx.x;
    if (n < HIDN * HIDN) {
        int r = n >> 9, h = n & 511;
        ws[n] = w_rec[h * HIDN + r];
    } else if (n < OFF_CI) {
        ws[n] = 0.0f;
    }
}

// C[r][h] = sum_k X[r][k] * Win[h][k], sequential ascending-k fp64 FMA chain per
// element (ARITHMETIC FROZEN: matches R1 bit-for-bit; downstream is chaotic).
// Retiled only: block tile 128x64, 256 threads, 8x4 micro-tile.
__global__ __launch_bounds__(256) void gemm_in(const float* __restrict__ X,
                                               const float* __restrict__ Win,
                                               float* __restrict__ C) {
    __shared__ float As[32][136];   // [k][row 0..127], padded
    __shared__ float Bs[32][72];    // [k][col 0..63], padded
    const int tid = threadIdx.x;
    const int tx = tid & 15;             // cols tx*4..+3
    const int ty = tid >> 4;             // rows ty*8..+7
    const int row0 = blockIdx.y * 128, col0 = blockIdx.x * 64;
    const int ar = tid >> 1, ak = (tid & 1) * 16;   // A staging: row, k-base
    const int br = tid >> 2, bk = (tid & 3) * 8;    // B staging
    double acc[8][4] = {};
    for (int k0 = 0; k0 < INF; k0 += 32) {
        __syncthreads();
#pragma unroll
        for (int q = 0; q < 4; ++q) {
            int kc = ak + q * 4, gk = k0 + kc;
            float4 va = make_float4(0.f, 0.f, 0.f, 0.f);
            if (gk < INF)   // INF%4==0, gk%4==0 -> full float4 in-bounds
                va = *(const float4*)(X + (size_t)(row0 + ar) * INF + gk);
            As[kc + 0][ar] = va.x; As[kc + 1][ar] = va.y;
            As[kc + 2][ar] = va.z; As[kc + 3][ar] = va.w;
        }
#pragma unroll
        for (int q = 0; q < 2; ++q) {
            int kc = bk + q * 4, gk = k0 + kc;
            float4 vb = make_float4(0.f, 0.f, 0.f, 0.f);
            if (gk < INF)
                vb = *(const float4*)(Win + (size_t)(col0 + br) * INF + gk);
            Bs[kc + 0][br] = vb.x; Bs[kc + 1][br] = vb.y;
            Bs[kc + 2][br] = vb.z; Bs[kc + 3][br] = vb.w;
        }
        __syncthreads();
#pragma unroll 8
        for (int kk = 0; kk < 32; ++kk) {
            float4 a0 = *(const float4*)&As[kk][ty * 8];
            float4 a1 = *(const float4*)&As[kk][ty * 8 + 4];
            float4 b4 = *(const float4*)&Bs[kk][tx * 4];
            double ad[8] = {(double)a0.x, (double)a0.y, (double)a0.z, (double)a0.w,
                            (double)a1.x, (double)a1.y, (double)a1.z, (double)a1.w};
            double bd[4] = {(double)b4.x, (double)b4.y, (double)b4.z, (double)b4.w};
#pragma unroll
            for (int i = 0; i < 8; ++i)
#pragma unroll
                for (int j = 0; j < 4; ++j)
                    acc[i][j] += ad[i] * bd[j];
        }
    }
#pragma unroll
    for (int i = 0; i < 8; ++i) {
        float4 o;
        o.x = (float)acc[i][0]; o.y = (float)acc[i][1];
        o.z = (float)acc[i][2]; o.w = (float)acc[i][3];
        *(float4*)(C + (size_t)(row0 + ty * 8 + i) * HIDN + col0 + tx * 4) = o;
    }
}

// Persistent fused stepper. grid=256 blocks = (32 batch-groups x 8 h-chunks),
// 512 threads: wave = one batch (8/block), lane = h within 64-h chunk.
// w_recT 512x64 slice staged ONCE in 128KB LDS; z exchanged via global
// double-buffered masks + hand-rolled grid barrier (1 block/CU: 148KB LDS).
// Gather/LI arithmetic VERBATIM from the R3-passing kernel (bit-identical).
__global__ __launch_bounds__(512) void fused_persist(const float* __restrict__ ci,
        const float* __restrict__ wT, const float* __restrict__ w_out,
        float* __restrict__ out, unsigned long long* __restrict__ zg,
        unsigned int* __restrict__ ctr) {
    __shared__ float wslice[512 * 64];    // 128 KB
    __shared__ float wout_s[NOUT * HIDN]; // 20 KB
    const int tid = threadIdx.x;
    const int wv = tid >> 6, lane = tid & 63;
    const int grp = (int)blockIdx.x >> 3, c = (int)blockIdx.x & 7;
    const int b = grp * 8 + wv;

    // stage this chunk's w_recT slice: wslice[r][l] = wT[r][c*64+l]
    for (int idx = tid; idx < 512 * 64; idx += 512) {
        int r = idx >> 6, l = idx & 63;
        wslice[idx] = wT[(size_t)r * HIDN + c * 64 + l];
    }
    for (int i = tid; i < NOUT * HIDN; i += 512) wout_s[i] = w_out[i];
    __syncthreads();

    unsigned long long m[8] = {0ull, 0ull, 0ull, 0ull, 0ull, 0ull, 0ull, 0ull};
    float pos = 0.0f;
    float v0 = 0.f, i0 = 0.f, v1 = 0.f, i1 = 0.f;   // LI state, lane 0 per wave

    for (int t = 0; t < TSTEPS; ++t) {
        float civ = ci[((size_t)t * NB + b) * HIDN + c * 64 + lane];

        // ---- recurrent gather with m = z_{t-1} (VERBATIM R3 arithmetic) ----
        float f[8] = {0.f, 0.f, 0.f, 0.f, 0.f, 0.f, 0.f, 0.f};
        unsigned long long mm[8];
#pragma unroll
        for (int c2 = 0; c2 < 8; ++c2) mm[c2] = m[c2];
        bool any = (mm[0] | mm[1] | mm[2] | mm[3] | mm[4] | mm[5] | mm[6] | mm[7]) != 0ull;
        while (any) {
            any = false;
#pragma unroll
            for (int c2 = 0; c2 < 8; ++c2) {
                if (mm[c2]) {
                    int bit = __builtin_ctzll(mm[c2]);
                    mm[c2] &= mm[c2] - 1;
                    f[c2] += wslice[(((c2 << 6) + bit) << 6) + lane];
                    any = true;
                }
            }
        }
        double acc = 0.0;
#pragma unroll
        for (int c2 = 0; c2 < 8; ++c2) acc += (double)f[c2];
        float rec32 = (float)acc;

        float cur = __fadd_rn(__fadd_rn(civ, rec32), 1e-4f);      // (in+rec)+I_APP
        float mc = __fmul_rn(2.5e5f, cur);                        // MU*cur
        pos = __fadd_rn(pos, __fmul_rn(1e-10f, mc));              // pos += DT*(..)
        bool zbit = __fsub_rn(pos, 2.5e-8f) > 0.0f;               // pos-W2 > 0
        pos = zbit ? 0.0f : pos;
        unsigned long long bal = __ballot(zbit ? 1 : 0);
        unsigned long long* zw = zg + (t & 1) * 2048;             // double buffer
        if (lane == 0)
            __hip_atomic_store(&zw[b * 8 + c], bal, __ATOMIC_RELEASE,
                               __HIP_MEMORY_SCOPE_AGENT);

        // ---- grid barrier: all 256 blocks published z_t ----
        __syncthreads();
        if (tid == 0) {
            __hip_atomic_fetch_add(ctr, 1u, __ATOMIC_ACQ_REL, __HIP_MEMORY_SCOPE_AGENT);
            unsigned int target = 256u * (unsigned)(t + 1);
            while (__hip_atomic_load(ctr, __ATOMIC_ACQUIRE,
                                     __HIP_MEMORY_SCOPE_AGENT) < target)
                __builtin_amdgcn_s_sleep(8);
        }
        __syncthreads();

        // ---- load z_t masks for this wave's batch ----
        unsigned long long w = 0ull;
        if (lane < 8)
            w = __hip_atomic_load(&zw[b * 8 + lane], __ATOMIC_ACQUIRE,
                                  __HIP_MEMORY_SCOPE_AGENT);
        unsigned int wlo = (unsigned int)w, whi = (unsigned int)(w >> 32);
#pragma unroll
        for (int c2 = 0; c2 < 8; ++c2) {
            unsigned int lo = (unsigned int)__shfl((int)wlo, c2);
            unsigned int hi = (unsigned int)__shfl((int)whi, c2);
            lo = __builtin_amdgcn_readfirstlane(lo);
            hi = __builtin_amdgcn_readfirstlane(hi);
            m[c2] = ((unsigned long long)hi << 32) | lo;
        }

        // ---- LI readout for step t using z_t (VERBATIM R3 arithmetic) ----
#pragma unroll
        for (int oo = 0; oo < 2; ++oo) {
            int o = (oo == 0) ? c : (c < 2 ? 8 + c : -1);
            if (o < 0) continue;
            double part = 0.0;
#pragma unroll
            for (int c2 = 0; c2 < 8; ++c2) {
                if ((m[c2] >> lane) & 1ull)
                    part += (double)wout_s[o * HIDN + c2 * 64 + lane];
            }
#pragma unroll
            for (int off = 32; off > 0; off >>= 1) part += __shfl_down(part, off);
            if (lane == 0) {
                float inp = (float)part;
                float vv = (oo == 0) ? v0 : v1;
                float ii = (oo == 0) ? i0 : i1;
                float vn = __fadd_rn(vv, __fmul_rn(1e-8f, __fsub_rn(ii, vv)));
                float t2 = __fmul_rn(2e-8f, ii);
                float in2 = __fadd_rn(__fsub_rn(ii, t2), inp);
                if (oo == 0) { v0 = vn; i0 = in2; } else { v1 = vn; i1 = in2; }
                out[((size_t)t * NB + b) * NOUT + o] = vn;
            }
        }
    }
}

extern "C" void kernel_launch(void* const* d_in, const int* in_sizes, int n_in,
                              void* d_out, int out_size, void* d_ws, size_t ws_size,
                              hipStream_t stream) {
    (void)in_sizes; (void)n_in; (void)out_size;
    const float* x     = (const float*)d_in[0];
    const float* w_in  = (const float*)d_in[1];
    const float* w_rec = (const float*)d_in[2];
    const float* w_out = (const float*)d_in[3];
    float* out = (float*)d_out;
    float* ws  = (float*)d_ws;
    if (ws_size < (size_t)WS_FLOATS * 4) return;

    float* wT = ws + OFF_WT;
    unsigned long long* zg = (unsigned long long*)(ws + OFF_ZG);
    unsigned int* ctr = (unsigned int*)(ws + OFF_CTR);
    float* ci = ws + OFF_CI;

    hipLaunchKernelGGL(init_kernel, dim3((OFF_CI + 255) / 256), dim3(256), 0,
                       stream, ws, w_rec);
    hipLaunchKernelGGL(gemm_in, dim3(8, 200), dim3(256), 0, stream, x, w_in, ci);
    hipLaunchKernelGGL(fused_persist, dim3(NB), dim3(512), 0, stream,
                       ci, wT, w_out, out, zg, ctr);
}

// Round 5
// 4765.891 us; speedup vs baseline: 1.2326x; 1.2326x over previous
//
#include <hip/hip_runtime.h>
#include <cstdint>
#include <cstddef>

#define TSTEPS 100
#define NB 256
#define INF 2312
#define HIDN 512
#define NOUT 10

// ws: only the input-projection cache
#define WS_FLOATS 13107200        // 52.4 MB

// C[r][h] = sum_k X[r][k] * Win[h][k]; per-element ascending-k fp64 FMA chain
// (ARITHMETIC FROZEN: identical to R1/R3-passing kernel; downstream is chaotic).
// Retiled: 128x128 block tile, 256 threads, 8x8 micro-tile, grid (4, 200).
__global__ __launch_bounds__(256, 2) void gemm_in(const float* __restrict__ X,
                                                  const float* __restrict__ Win,
                                                  float* __restrict__ C) {
    __shared__ float As[32][136];   // [k][row], padded
    __shared__ float Bs[32][136];   // [k][col], padded
    const int tid = threadIdx.x;
    const int tx = tid & 15;             // cols tx*8..+7
    const int ty = tid >> 4;             // rows ty*8..+7
    const int row0 = blockIdx.y * 128, col0 = blockIdx.x * 128;
    const int sr = tid >> 1, sk = (tid & 1) * 16;   // staging: row/col, k-base
    double acc[8][8] = {};
    for (int k0 = 0; k0 < INF; k0 += 32) {
        __syncthreads();
#pragma unroll
        for (int q = 0; q < 4; ++q) {
            int kc = sk + q * 4, gk = k0 + kc;
            float4 va = make_float4(0.f, 0.f, 0.f, 0.f);
            float4 vb = make_float4(0.f, 0.f, 0.f, 0.f);
            if (gk < INF) {   // INF%4==0, gk%4==0 -> full float4 in-bounds
                va = *(const float4*)(X + (size_t)(row0 + sr) * INF + gk);
                vb = *(const float4*)(Win + (size_t)(col0 + sr) * INF + gk);
            }
            As[kc + 0][sr] = va.x; As[kc + 1][sr] = va.y;
            As[kc + 2][sr] = va.z; As[kc + 3][sr] = va.w;
            Bs[kc + 0][sr] = vb.x; Bs[kc + 1][sr] = vb.y;
            Bs[kc + 2][sr] = vb.z; Bs[kc + 3][sr] = vb.w;
        }
        __syncthreads();
#pragma unroll 4
        for (int kk = 0; kk < 32; ++kk) {
            float4 a0 = *(const float4*)&As[kk][ty * 8];
            float4 a1 = *(const float4*)&As[kk][ty * 8 + 4];
            float4 b0 = *(const float4*)&Bs[kk][tx * 8];
            float4 b1 = *(const float4*)&Bs[kk][tx * 8 + 4];
            double ad[8] = {(double)a0.x, (double)a0.y, (double)a0.z, (double)a0.w,
                            (double)a1.x, (double)a1.y, (double)a1.z, (double)a1.w};
            double bd[8] = {(double)b0.x, (double)b0.y, (double)b0.z, (double)b0.w,
                            (double)b1.x, (double)b1.y, (double)b1.z, (double)b1.w};
#pragma unroll
            for (int i = 0; i < 8; ++i)
#pragma unroll
                for (int j = 0; j < 8; ++j)
                    acc[i][j] += ad[i] * bd[j];
        }
    }
#pragma unroll
    for (int i = 0; i < 8; ++i) {
#pragma unroll
        for (int jj = 0; jj < 2; ++jj) {
            float4 o;
            o.x = (float)acc[i][jj * 4 + 0]; o.y = (float)acc[i][jj * 4 + 1];
            o.z = (float)acc[i][jj * 4 + 2]; o.w = (float)acc[i][jj * 4 + 3];
            *(float4*)(C + (size_t)(row0 + ty * 8 + i) * HIDN + col0 + tx * 8 + jj * 4) = o;
        }
    }
}

// Fused 100 steps, block = 2 batches (NBAT=2), 128 blocks x 512 threads.
// Thread = h; serves both batches from ONE w_rec-row load stream (halves L2 BW).
// Dense-ized gather: unconditional float4 row loads + select-add in ascending
// bit order (+0.0f adds are bit-identity); wave-uniform word-skip when both
// masks are zero. z exchange via LDS ballots, ONE __syncthreads per step,
// no grid sync. All fp arithmetic VERBATIM from the R3-passing kernel.
__global__ __launch_bounds__(512) void fused2(const float* __restrict__ ci,
        const float* __restrict__ w_rec, const float* __restrict__ w_out,
        float* __restrict__ out) {
    __shared__ unsigned long long zlds[2][2][8];   // [t&1][batch][wave]
    __shared__ float wout_s[NOUT * HIDN];          // 20 KB
    const int tid = threadIdx.x;
    const int wv = tid >> 6, lane = tid & 63;
    const int h = tid;
    const int b0 = (int)blockIdx.x * 2;
    const float* rowp = w_rec + (size_t)h * HIDN;

    for (int i = tid; i < NOUT * HIDN; i += 512) wout_s[i] = w_out[i];
    __syncthreads();

    unsigned long long m0[8] = {0ull,0ull,0ull,0ull,0ull,0ull,0ull,0ull};
    unsigned long long m1[8] = {0ull,0ull,0ull,0ull,0ull,0ull,0ull,0ull};
    float pos0 = 0.f, pos1 = 0.f;
    const int og = wv >> 1, nb = wv & 1;           // wave -> (output-group, batch)
    const int nout_w = (og < 2) ? 3 : 2;           // o = og, og+4, og+8(<10)
    float vv[3] = {0.f, 0.f, 0.f}, ii[3] = {0.f, 0.f, 0.f};

    for (int t = 0; t < TSTEPS; ++t) {
        float civ0 = ci[((size_t)t * NB + b0) * HIDN + h];
        float civ1 = ci[((size_t)t * NB + b0 + 1) * HIDN + h];

        // ---- recurrent gather for both batches (frozen arithmetic) ----
        double acc0 = 0.0, acc1 = 0.0;
#pragma unroll
        for (int c2 = 0; c2 < 8; ++c2) {
            float f0 = 0.f, f1 = 0.f;
            const unsigned long long um0 = m0[c2], um1 = m1[c2];
            if (um0 | um1) {                       // wave-uniform branch
                const float* wp = rowp + (c2 << 6);
#pragma unroll
                for (int q = 0; q < 16; ++q) {
                    float4 w4 = *(const float4*)(wp + q * 4);
                    unsigned int ba = (unsigned int)(um0 >> (q * 4)) & 15u;
                    unsigned int bb = (unsigned int)(um1 >> (q * 4)) & 15u;
                    f0 = __fadd_rn(f0, (ba & 1u) ? w4.x : 0.0f);
                    f0 = __fadd_rn(f0, (ba & 2u) ? w4.y : 0.0f);
                    f0 = __fadd_rn(f0, (ba & 4u) ? w4.z : 0.0f);
                    f0 = __fadd_rn(f0, (ba & 8u) ? w4.w : 0.0f);
                    f1 = __fadd_rn(f1, (bb & 1u) ? w4.x : 0.0f);
                    f1 = __fadd_rn(f1, (bb & 2u) ? w4.y : 0.0f);
                    f1 = __fadd_rn(f1, (bb & 4u) ? w4.z : 0.0f);
                    f1 = __fadd_rn(f1, (bb & 8u) ? w4.w : 0.0f);
                }
            }
            acc0 += (double)f0;                    // ascending-c2 fp64 combine
            acc1 += (double)f1;
        }
        float rec0 = (float)acc0, rec1 = (float)acc1;

        // ---- membrane update + spike (frozen) ----
        float cur0 = __fadd_rn(__fadd_rn(civ0, rec0), 1e-4f);
        float mc0 = __fmul_rn(2.5e5f, cur0);
        pos0 = __fadd_rn(pos0, __fmul_rn(1e-10f, mc0));
        bool z0 = __fsub_rn(pos0, 2.5e-8f) > 0.0f;
        pos0 = z0 ? 0.0f : pos0;
        float cur1 = __fadd_rn(__fadd_rn(civ1, rec1), 1e-4f);
        float mc1 = __fmul_rn(2.5e5f, cur1);
        pos1 = __fadd_rn(pos1, __fmul_rn(1e-10f, mc1));
        bool z1 = __fsub_rn(pos1, 2.5e-8f) > 0.0f;
        pos1 = z1 ? 0.0f : pos1;

        unsigned long long bal0 = __ballot(z0 ? 1 : 0);
        unsigned long long bal1 = __ballot(z1 ? 1 : 0);
        if (lane == 0) {
            zlds[t & 1][0][wv] = bal0;
            zlds[t & 1][1][wv] = bal1;
        }
        __syncthreads();   // publish z_t (double-buffered in t -> one barrier/step)

        // ---- refresh uniform masks (SGPR) for LI + next gather ----
#pragma unroll
        for (int c2 = 0; c2 < 8; ++c2) {
            unsigned long long w0 = zlds[t & 1][0][c2];
            unsigned long long w1 = zlds[t & 1][1][c2];
            unsigned int l0 = __builtin_amdgcn_readfirstlane((unsigned int)w0);
            unsigned int h0 = __builtin_amdgcn_readfirstlane((unsigned int)(w0 >> 32));
            unsigned int l1 = __builtin_amdgcn_readfirstlane((unsigned int)w1);
            unsigned int h1 = __builtin_amdgcn_readfirstlane((unsigned int)(w1 >> 32));
            m0[c2] = ((unsigned long long)h0 << 32) | l0;
            m1[c2] = ((unsigned long long)h1 << 32) | l1;
        }

        // ---- LI readout for step t (frozen; wave -> batch nb, outputs og+4j) ----
#pragma unroll
        for (int j = 0; j < 3; ++j) {
            if (j < nout_w) {
                const int o = og + 4 * j;
                double part = 0.0;
#pragma unroll
                for (int c2 = 0; c2 < 8; ++c2) {
                    unsigned long long mb = nb ? m1[c2] : m0[c2];
                    if ((mb >> lane) & 1ull)
                        part += (double)wout_s[o * HIDN + (c2 << 6) + lane];
                }
#pragma unroll
                for (int off = 32; off > 0; off >>= 1) part += __shfl_down(part, off);
                if (lane == 0) {
                    float inp = (float)part;
                    float vn = __fadd_rn(vv[j], __fmul_rn(1e-8f, __fsub_rn(ii[j], vv[j])));
                    float t2 = __fmul_rn(2e-8f, ii[j]);
                    float in2 = __fadd_rn(__fsub_rn(ii[j], t2), inp);
                    vv[j] = vn; ii[j] = in2;
                    out[((size_t)t * NB + b0 + nb) * NOUT + o] = vn;
                }
            }
        }
    }
}

extern "C" void kernel_launch(void* const* d_in, const int* in_sizes, int n_in,
                              void* d_out, int out_size, void* d_ws, size_t ws_size,
                              hipStream_t stream) {
    (void)in_sizes; (void)n_in; (void)out_size;
    const float* x     = (const float*)d_in[0];
    const float* w_in  = (const float*)d_in[1];
    const float* w_rec = (const float*)d_in[2];
    const float* w_out = (const float*)d_in[3];
    float* out = (float*)d_out;
    float* ci  = (float*)d_ws;
    if (ws_size < (size_t)WS_FLOATS * 4) return;

    hipLaunchKernelGGL(gemm_in, dim3(4, 200), dim3(256), 0, stream, x, w_in, ci);
    hipLaunchKernelGGL(fused2, dim3(NB / 2), dim3(512), 0, stream,
                       ci, w_rec, w_out, out);
}